// Round 10
// baseline (52.300 us; speedup 1.0000x reference)
//
#include <hip/hip_runtime.h>
#include <math.h>

// LightingProbes R10: R8 shell (1pt/thread, LDS-staged I/O, 16B shared-exp
// patches, 3.07MB table) + (a) non-temporal gather loads (no L1 alloc for the
// 0%-hit table; possibly smaller L2->TCP granularity), (b) provable rank-0
// (candidate 000) gather issued BEFORE the insert chain, (c) 3-level inserts
// for ranks 1-3 only. Selection set + all arithmetic identical to R8.

#define NPATCH 192000            // 6*16*16*125 patches

typedef float vf4 __attribute__((ext_vector_type(4)));
typedef unsigned int u32x4 __attribute__((ext_vector_type(4)));

__device__ __forceinline__ float fastrcp(float x)  { return __builtin_amdgcn_rcpf(x); }
__device__ __forceinline__ float fastsqrt(float x) { return __builtin_amdgcn_sqrtf(x); }

__device__ __forceinline__ void dimsort(float v,
    float& e0, float& e1, float& e2, int& c0, int& c1, int& c2)
{
    float f = (v + 3.0f) * (1.0f / 1.5f);
    int n = (int)floorf(f + 0.5f);
    n = n < 0 ? 0 : (n > 4 ? 4 : n);
    int s = n - 1;
    s = s < 0 ? 0 : (s > 2 ? 2 : s);

    float p0 = fmaf(1.5f, (float)s, -3.0f);
    float d0 = v - p0;
    float d1 = d0 - 1.5f;
    float d2 = d1 - 1.5f;
    float a0 = d0 * d0, a1 = d1 * d1, a2 = d2 * d2;
    int j0 = s, j1 = s + 1, j2 = s + 2;

    {   bool sw = a1 < a0;
        float ta = sw ? a1 : a0, tb = sw ? a0 : a1;
        int   ua = sw ? j1 : j0, ub = sw ? j0 : j1;
        a0 = ta; a1 = tb; j0 = ua; j1 = ub; }
    {   bool sw = a2 < a1;
        float ta = sw ? a2 : a1, tb = sw ? a1 : a2;
        int   ua = sw ? j2 : j1, ub = sw ? j1 : j2;
        a1 = ta; a2 = tb; j1 = ua; j2 = ub; }
    {   bool sw = a1 < a0;
        float ta = sw ? a1 : a0, tb = sw ? a0 : a1;
        int   ua = sw ? j1 : j0, ub = sw ? j0 : j1;
        a0 = ta; a1 = tb; j0 = ua; j1 = ub; }

    e0 = a0; e1 = a1; e2 = a2;
    c0 = j0; c1 = j1; c2 = j2;
}

// 3-level insert into ranks 1..3 (rank 0 fixed: d >= s0 guaranteed, ties go
// to rank 1 which matches reference index-order since any tie with the 000
// candidate has a larger probe index).
#define INSERT3(d, L, s1, s2, s3, k1, k2, k3)                                 \
    {                                                                         \
        bool lt = (d) < s3; s3 = lt ? (d) : s3; k3 = lt ? (L) : k3;           \
        { bool cb = s3 < s2; float nd = cb ? s3 : s2, xd = cb ? s2 : s3;      \
          int ni = cb ? k3 : k2, xi = cb ? k2 : k3;                           \
          s2 = nd; s3 = xd; k2 = ni; k3 = xi; }                               \
        { bool cb = s2 < s1; float nd = cb ? s2 : s1, xd = cb ? s1 : s2;      \
          int ni = cb ? k2 : k1, xi = cb ? k1 : k2;                           \
          s1 = nd; s2 = xd; k1 = ni; k2 = xi; }                               \
    }

__device__ __forceinline__ void uv_setup(
    float dx, float dy, float dz,
    int& face, int& t00,
    float& w00, float& w01, float& w10, float& w11)
{
    float nrm = sqrtf(fmaf(dx, dx, fmaf(dy, dy, dz * dz)));
    nrm = fmaxf(nrm, 1e-12f);
    float inv = fastrcp(nrm);
    float ux = dx * inv, uy = dy * inv, uz = dz * inv;
    float ax = fabsf(ux), ay = fabsf(uy), az = fabsf(uz);

    bool xd = (ax >= ay) && (ax >= az);
    float den, un, vn;
    if (xd) {
        face = (ux > 0.0f) ? 0 : 1;
        den = ax; un = (ux > 0.0f) ? -uz : uz; vn = -uy;
    } else if (ay >= az) {
        face = (uy > 0.0f) ? 2 : 3;
        den = ay; un = ux; vn = (uy > 0.0f) ? uz : -uz;
    } else {
        face = (uz > 0.0f) ? 4 : 5;
        den = az; un = (uz > 0.0f) ? ux : -ux; vn = -uy;
    }
    float rden = fastrcp(den + 1e-8f);
    float u = un * rden;
    float v = vn * rden;
    u = fminf(1.0f, fmaxf(-1.0f, u));
    v = fminf(1.0f, fmaxf(-1.0f, v));

    float fx = (u + 1.0f) * 0.5f * 15.0f;
    float fy = (v + 1.0f) * 0.5f * 15.0f;
    float x0f = floorf(fx), y0f = floorf(fy);
    float wx = fx - x0f, wy = fy - y0f;
    int px0 = (int)x0f; px0 = px0 < 0 ? 0 : (px0 > 15 ? 15 : px0);
    int py0 = (int)y0f; py0 = py0 < 0 ? 0 : (py0 > 15 ? 15 : py0);

    w00 = (1.0f - wx) * (1.0f - wy);
    w01 = wx * (1.0f - wy);
    w10 = (1.0f - wx) * wy;
    w11 = wx * wy;

    t00 = py0 * 16 + px0;
}

__device__ __forceinline__ float dec(unsigned w, int sh) {
    return (float)(((int)(w << (22 - sh))) >> 22);
}

__device__ __forceinline__ void decode_accum(
    u32x4 pw, float wn,
    float w00, float w01, float w10, float w11,
    float& r, float& g, float& b)
{
    int E = (int)((pw.x >> 30) | (((pw.y >> 30) & 3u) << 2) | (((pw.z >> 30) & 3u) << 4));
    float s = __uint_as_float((unsigned)(E + 87) << 23);   // 2^(E-40)
    float wns = wn * s;

    float r00 = dec(pw.x, 0),  g00 = dec(pw.x, 10), b00 = dec(pw.x, 20);
    float r01 = dec(pw.y, 0),  g01 = dec(pw.y, 10), b01 = dec(pw.y, 20);
    float r10 = dec(pw.z, 0),  g10 = dec(pw.z, 10), b10 = dec(pw.z, 20);
    float r11 = dec(pw.w, 0),  g11 = dec(pw.w, 10), b11 = dec(pw.w, 20);

    float rr = fmaf(r00, w00, fmaf(r01, w01, fmaf(r10, w10, r11 * w11)));
    float gg = fmaf(g00, w00, fmaf(g01, w01, fmaf(g10, w10, g11 * w11)));
    float bv = fmaf(b00, w00, fmaf(b01, w01, fmaf(b10, w10, b11 * w11)));
    r = fmaf(wns, rr, r);
    g = fmaf(wns, gg, g);
    b = fmaf(wns, bv, b);
}

// ---- build 16B shared-exp patches (identical to R8) ----
__global__ __launch_bounds__(256) void build_patches_se(
    const float* __restrict__ cube, u32x4* __restrict__ patches)
{
    int t = blockIdx.x * blockDim.x + threadIdx.x;
    if (t >= NPATCH) return;
    int p   = t % 125;
    int q   = t / 125;
    int px0 = q % 16; q /= 16;
    int py0 = q % 16;
    int face = q / 16;
    int px1 = px0 + 1 > 15 ? 15 : px0 + 1;
    int py1 = py0 + 1 > 15 ? 15 : py0 + 1;

    const float* f = cube + (p * 6 + face) * 768;
    int o00 = (py0 * 16 + px0) * 3;
    int o01 = (py0 * 16 + px1) * 3;
    int o10 = (py1 * 16 + px0) * 3;
    int o11 = (py1 * 16 + px1) * 3;

    float v[12];
    v[0] = f[o00]; v[1]  = f[o00 + 1]; v[2]  = f[o00 + 2];
    v[3] = f[o01]; v[4]  = f[o01 + 1]; v[5]  = f[o01 + 2];
    v[6] = f[o10]; v[7]  = f[o10 + 1]; v[8]  = f[o10 + 2];
    v[9] = f[o11]; v[10] = f[o11 + 1]; v[11] = f[o11 + 2];

    float mx = 0.0f;
#pragma unroll
    for (int j = 0; j < 12; j++) mx = fmaxf(mx, fabsf(v[j]));

    int E;
    if (mx == 0.0f) {
        E = 0;
    } else {
        unsigned mb = __float_as_uint(mx);
        int eb = (int)((mb >> 23) & 0xFF) - 127;
        E = eb + 32;
        E = E < 0 ? 0 : (E > 63 ? 63 : E);
    }
    float mscale = __uint_as_float((unsigned)(167 - E) << 23);   // 2^(40-E)

    unsigned m[12];
#pragma unroll
    for (int j = 0; j < 12; j++) {
        float s = rintf(v[j] * mscale);
        s = fminf(511.0f, fmaxf(-511.0f, s));
        m[j] = (unsigned)((int)s) & 0x3FF;
    }

    unsigned w0 = m[0] | (m[1] << 10) | (m[2] << 20) | (((unsigned)E & 3) << 30);
    unsigned w1 = m[3] | (m[4] << 10) | (m[5] << 20) | ((((unsigned)E >> 2) & 3) << 30);
    unsigned w2 = m[6] | (m[7] << 10) | (m[8] << 20) | ((((unsigned)E >> 4) & 3) << 30);
    unsigned w3 = m[9] | (m[10] << 10) | (m[11] << 20);

    u32x4 o = {w0, w1, w2, w3};
    patches[t] = o;
}

__global__ __launch_bounds__(256) void lp_se3(
    const float* __restrict__ xyz,
    const float* __restrict__ vdirs,
    const u32x4* __restrict__ patches,
    float* __restrict__ out,
    int N)
{
    __shared__ float sh[1536];

    int tid = threadIdx.x;
    int b0  = blockIdx.x * 256;
    int nPts = N - b0; nPts = nPts > 256 ? 256 : nPts;
    int nflt = nPts * 3;
    int base4 = (b0 * 3) >> 2;

    const vf4* x4 = (const vf4*)xyz;
    const vf4* d4 = (const vf4*)vdirs;
    if (tid * 4 < nflt) {
        vf4 vx = __builtin_nontemporal_load(&x4[base4 + tid]);
        ((vf4*)sh)[tid] = vx;
        vf4 vd = __builtin_nontemporal_load(&d4[base4 + tid]);
        ((vf4*)(sh + 768))[tid] = vd;
    }
    __syncthreads();

    float r = 0.0f, g = 0.0f, b = 0.0f;
    if (tid < nPts) {
        float x  = sh[3 * tid + 0];
        float y  = sh[3 * tid + 1];
        float z  = sh[3 * tid + 2];
        float dx = sh[768 + 3 * tid + 0];
        float dy = sh[768 + 3 * tid + 1];
        float dz = sh[768 + 3 * tid + 2];

        // ---- per-dim sort + uv first (independent), then issue rank-0 gather
        float ex0, ex1, ex2, ey0, ey1, ey2, ez0, ez1, ez2;
        int jx0, jx1, jx2, jy0, jy1, jy2, jz0, jz1, jz2;
        dimsort(x, ex0, ex1, ex2, jx0, jx1, jx2);
        dimsort(y, ey0, ey1, ey2, jy0, jy1, jy2);
        dimsort(z, ez0, ez1, ez2, jz0, jz1, jz2);

        int face, t00;
        float w00, w01, w10, w11;
        uv_setup(dx, dy, dz, face, t00, w00, w01, w10, w11);
        int cell = (face * 256 + t00) * 125;

        int X0 = jx0 * 25, X1 = jx1 * 25, X2 = jx2 * 25;
        int Y0 = jy0 * 5,  Y1 = jy1 * 5,  Y2 = jy2 * 5;
        int Z0 = jz0,      Z1 = jz1,      Z2 = jz2;

        // rank-0 is ALWAYS candidate 000 (sum of per-dim minima; strict-<
        // inserts never displace it; reference tie-break agrees). Issue its
        // gather before the insert chain to overlap latency with VALU.
        int k0 = X0 + Y0 + Z0;
        u32x4 pw0 = __builtin_nontemporal_load(&patches[cell + k0]);

        float exy00 = ex0 + ey0, exy10 = ex1 + ey0, exy01 = ex0 + ey1;
        float exy11 = ex1 + ey1, exy20 = ex2 + ey0, exy02 = ex0 + ey2;
        int   kxy10 = X1 + Y0,   kxy01 = X0 + Y1;
        int   kxy11 = X1 + Y1,   kxy20 = X2 + Y0,   kxy02 = X0 + Y2;
        int   kxy00 = X0 + Y0;

        float s0 = exy00 + ez0;
        float s1 = 1e30f, s2 = 1e30f, s3 = 1e30f;
        int   k1 = 0, k2 = 0, k3 = 0;

        { float d = exy10 + ez0; int L = kxy10 + Z0; INSERT3(d, L, s1, s2, s3, k1, k2, k3); }
        { float d = exy01 + ez0; int L = kxy01 + Z0; INSERT3(d, L, s1, s2, s3, k1, k2, k3); }
        { float d = exy00 + ez1; int L = kxy00 + Z1; INSERT3(d, L, s1, s2, s3, k1, k2, k3); }
        { float d = exy11 + ez0; int L = kxy11 + Z0; INSERT3(d, L, s1, s2, s3, k1, k2, k3); }
        { float d = exy10 + ez1; int L = kxy10 + Z1; INSERT3(d, L, s1, s2, s3, k1, k2, k3); }
        { float d = exy01 + ez1; int L = kxy01 + Z1; INSERT3(d, L, s1, s2, s3, k1, k2, k3); }
        { float d = exy20 + ez0; int L = kxy20 + Z0; INSERT3(d, L, s1, s2, s3, k1, k2, k3); }
        { float d = exy02 + ez0; int L = kxy02 + Z0; INSERT3(d, L, s1, s2, s3, k1, k2, k3); }
        { float d = exy00 + ez2; int L = kxy00 + Z2; INSERT3(d, L, s1, s2, s3, k1, k2, k3); }

        // remaining 3 gathers (non-temporal: no L1 allocation)
        u32x4 pw1 = __builtin_nontemporal_load(&patches[cell + k1]);
        u32x4 pw2 = __builtin_nontemporal_load(&patches[cell + k2]);
        u32x4 pw3 = __builtin_nontemporal_load(&patches[cell + k3]);

        float w0 = fastrcp(fastsqrt(s0) + 1e-4f);
        float w1 = fastrcp(fastsqrt(s1) + 1e-4f);
        float w2 = fastrcp(fastsqrt(s2) + 1e-4f);
        float w3 = fastrcp(fastsqrt(s3) + 1e-4f);
        float wi = fastrcp(w0 + w1 + w2 + w3);
        w0 *= wi; w1 *= wi; w2 *= wi; w3 *= wi;

        decode_accum(pw0, w0, w00, w01, w10, w11, r, g, b);
        decode_accum(pw1, w1, w00, w01, w10, w11, r, g, b);
        decode_accum(pw2, w2, w00, w01, w10, w11, r, g, b);
        decode_accum(pw3, w3, w00, w01, w10, w11, r, g, b);
    }

    __syncthreads();
    if (tid < nPts) {
        sh[3 * tid + 0] = r;
        sh[3 * tid + 1] = g;
        sh[3 * tid + 2] = b;
    }
    __syncthreads();
    if (tid * 4 < nflt) {
        vf4* o4 = (vf4*)out;
        __builtin_nontemporal_store(((vf4*)sh)[tid], &o4[base4 + tid]);
    }
}

extern "C" void kernel_launch(void* const* d_in, const int* in_sizes, int n_in,
                              void* d_out, int out_size, void* d_ws, size_t ws_size,
                              hipStream_t stream) {
    const float* xyz  = (const float*)d_in[0];
    const float* vd   = (const float*)d_in[1];
    const float* cube = (const float*)d_in[2];
    float* outp = (float*)d_out;
    int N = in_sizes[0] / 3;
    int blocks = (N + 255) / 256;

    u32x4* patches = (u32x4*)d_ws;    // 3.07 MB
    hipLaunchKernelGGL(build_patches_se, dim3((NPATCH + 255) / 256), dim3(256), 0, stream,
                       cube, patches);
    hipLaunchKernelGGL(lp_se3, dim3(blocks), dim3(256), 0, stream,
                       xyz, vd, patches, outp, N);
}

// Round 11
// 34.675 us; speedup vs baseline: 1.5083x; 1.5083x over previous
//
#include <hip/hip_runtime.h>
#include <math.h>

// LightingProbes R11: R10 minus the NT-gather mistake (patch loads back to
// cached; NT evict-first had pushed the 3MB table out of L2 -> 43us).
// Keeps: rank-0(000) gather hoisted before the insert chain, 3-level INSERT
// (ranks 1-3), 16B shared-exp patches, LDS-staged NT streaming I/O.
// Selection set + arithmetic identical to R8/R10 (absmax must be 1.953e-3).

#define NPATCH 192000            // 6*16*16*125 patches

typedef float vf4 __attribute__((ext_vector_type(4)));
typedef unsigned int u32x4 __attribute__((ext_vector_type(4)));

__device__ __forceinline__ float fastrcp(float x)  { return __builtin_amdgcn_rcpf(x); }
__device__ __forceinline__ float fastsqrt(float x) { return __builtin_amdgcn_sqrtf(x); }

__device__ __forceinline__ void dimsort(float v,
    float& e0, float& e1, float& e2, int& c0, int& c1, int& c2)
{
    float f = (v + 3.0f) * (1.0f / 1.5f);
    int n = (int)floorf(f + 0.5f);
    n = n < 0 ? 0 : (n > 4 ? 4 : n);
    int s = n - 1;
    s = s < 0 ? 0 : (s > 2 ? 2 : s);

    float p0 = fmaf(1.5f, (float)s, -3.0f);
    float d0 = v - p0;
    float d1 = d0 - 1.5f;
    float d2 = d1 - 1.5f;
    float a0 = d0 * d0, a1 = d1 * d1, a2 = d2 * d2;
    int j0 = s, j1 = s + 1, j2 = s + 2;

    {   bool sw = a1 < a0;
        float ta = sw ? a1 : a0, tb = sw ? a0 : a1;
        int   ua = sw ? j1 : j0, ub = sw ? j0 : j1;
        a0 = ta; a1 = tb; j0 = ua; j1 = ub; }
    {   bool sw = a2 < a1;
        float ta = sw ? a2 : a1, tb = sw ? a1 : a2;
        int   ua = sw ? j2 : j1, ub = sw ? j1 : j2;
        a1 = ta; a2 = tb; j1 = ua; j2 = ub; }
    {   bool sw = a1 < a0;
        float ta = sw ? a1 : a0, tb = sw ? a0 : a1;
        int   ua = sw ? j1 : j0, ub = sw ? j0 : j1;
        a0 = ta; a1 = tb; j0 = ua; j1 = ub; }

    e0 = a0; e1 = a1; e2 = a2;
    c0 = j0; c1 = j1; c2 = j2;
}

#define INSERT3(d, L, s1, s2, s3, k1, k2, k3)                                 \
    {                                                                         \
        bool lt = (d) < s3; s3 = lt ? (d) : s3; k3 = lt ? (L) : k3;           \
        { bool cb = s3 < s2; float nd = cb ? s3 : s2, xd = cb ? s2 : s3;      \
          int ni = cb ? k3 : k2, xi = cb ? k2 : k3;                           \
          s2 = nd; s3 = xd; k2 = ni; k3 = xi; }                               \
        { bool cb = s2 < s1; float nd = cb ? s2 : s1, xd = cb ? s1 : s2;      \
          int ni = cb ? k2 : k1, xi = cb ? k1 : k2;                           \
          s1 = nd; s2 = xd; k1 = ni; k2 = xi; }                               \
    }

__device__ __forceinline__ void uv_setup(
    float dx, float dy, float dz,
    int& face, int& t00,
    float& w00, float& w01, float& w10, float& w11)
{
    float nrm = sqrtf(fmaf(dx, dx, fmaf(dy, dy, dz * dz)));
    nrm = fmaxf(nrm, 1e-12f);
    float inv = fastrcp(nrm);
    float ux = dx * inv, uy = dy * inv, uz = dz * inv;
    float ax = fabsf(ux), ay = fabsf(uy), az = fabsf(uz);

    bool xd = (ax >= ay) && (ax >= az);
    float den, un, vn;
    if (xd) {
        face = (ux > 0.0f) ? 0 : 1;
        den = ax; un = (ux > 0.0f) ? -uz : uz; vn = -uy;
    } else if (ay >= az) {
        face = (uy > 0.0f) ? 2 : 3;
        den = ay; un = ux; vn = (uy > 0.0f) ? uz : -uz;
    } else {
        face = (uz > 0.0f) ? 4 : 5;
        den = az; un = (uz > 0.0f) ? ux : -ux; vn = -uy;
    }
    float rden = fastrcp(den + 1e-8f);
    float u = un * rden;
    float v = vn * rden;
    u = fminf(1.0f, fmaxf(-1.0f, u));
    v = fminf(1.0f, fmaxf(-1.0f, v));

    float fx = (u + 1.0f) * 0.5f * 15.0f;
    float fy = (v + 1.0f) * 0.5f * 15.0f;
    float x0f = floorf(fx), y0f = floorf(fy);
    float wx = fx - x0f, wy = fy - y0f;
    int px0 = (int)x0f; px0 = px0 < 0 ? 0 : (px0 > 15 ? 15 : px0);
    int py0 = (int)y0f; py0 = py0 < 0 ? 0 : (py0 > 15 ? 15 : py0);

    w00 = (1.0f - wx) * (1.0f - wy);
    w01 = wx * (1.0f - wy);
    w10 = (1.0f - wx) * wy;
    w11 = wx * wy;

    t00 = py0 * 16 + px0;
}

__device__ __forceinline__ float dec(unsigned w, int sh) {
    return (float)(((int)(w << (22 - sh))) >> 22);
}

__device__ __forceinline__ void decode_accum(
    u32x4 pw, float wn,
    float w00, float w01, float w10, float w11,
    float& r, float& g, float& b)
{
    int E = (int)((pw.x >> 30) | (((pw.y >> 30) & 3u) << 2) | (((pw.z >> 30) & 3u) << 4));
    float s = __uint_as_float((unsigned)(E + 87) << 23);   // 2^(E-40)
    float wns = wn * s;

    float r00 = dec(pw.x, 0),  g00 = dec(pw.x, 10), b00 = dec(pw.x, 20);
    float r01 = dec(pw.y, 0),  g01 = dec(pw.y, 10), b01 = dec(pw.y, 20);
    float r10 = dec(pw.z, 0),  g10 = dec(pw.z, 10), b10 = dec(pw.z, 20);
    float r11 = dec(pw.w, 0),  g11 = dec(pw.w, 10), b11 = dec(pw.w, 20);

    float rr = fmaf(r00, w00, fmaf(r01, w01, fmaf(r10, w10, r11 * w11)));
    float gg = fmaf(g00, w00, fmaf(g01, w01, fmaf(g10, w10, g11 * w11)));
    float bv = fmaf(b00, w00, fmaf(b01, w01, fmaf(b10, w10, b11 * w11)));
    r = fmaf(wns, rr, r);
    g = fmaf(wns, gg, g);
    b = fmaf(wns, bv, b);
}

// ---- build 16B shared-exp patches (identical to R8) ----
__global__ __launch_bounds__(256) void build_patches_se(
    const float* __restrict__ cube, u32x4* __restrict__ patches)
{
    int t = blockIdx.x * blockDim.x + threadIdx.x;
    if (t >= NPATCH) return;
    int p   = t % 125;
    int q   = t / 125;
    int px0 = q % 16; q /= 16;
    int py0 = q % 16;
    int face = q / 16;
    int px1 = px0 + 1 > 15 ? 15 : px0 + 1;
    int py1 = py0 + 1 > 15 ? 15 : py0 + 1;

    const float* f = cube + (p * 6 + face) * 768;
    int o00 = (py0 * 16 + px0) * 3;
    int o01 = (py0 * 16 + px1) * 3;
    int o10 = (py1 * 16 + px0) * 3;
    int o11 = (py1 * 16 + px1) * 3;

    float v[12];
    v[0] = f[o00]; v[1]  = f[o00 + 1]; v[2]  = f[o00 + 2];
    v[3] = f[o01]; v[4]  = f[o01 + 1]; v[5]  = f[o01 + 2];
    v[6] = f[o10]; v[7]  = f[o10 + 1]; v[8]  = f[o10 + 2];
    v[9] = f[o11]; v[10] = f[o11 + 1]; v[11] = f[o11 + 2];

    float mx = 0.0f;
#pragma unroll
    for (int j = 0; j < 12; j++) mx = fmaxf(mx, fabsf(v[j]));

    int E;
    if (mx == 0.0f) {
        E = 0;
    } else {
        unsigned mb = __float_as_uint(mx);
        int eb = (int)((mb >> 23) & 0xFF) - 127;
        E = eb + 32;
        E = E < 0 ? 0 : (E > 63 ? 63 : E);
    }
    float mscale = __uint_as_float((unsigned)(167 - E) << 23);   // 2^(40-E)

    unsigned m[12];
#pragma unroll
    for (int j = 0; j < 12; j++) {
        float s = rintf(v[j] * mscale);
        s = fminf(511.0f, fmaxf(-511.0f, s));
        m[j] = (unsigned)((int)s) & 0x3FF;
    }

    unsigned w0 = m[0] | (m[1] << 10) | (m[2] << 20) | (((unsigned)E & 3) << 30);
    unsigned w1 = m[3] | (m[4] << 10) | (m[5] << 20) | ((((unsigned)E >> 2) & 3) << 30);
    unsigned w2 = m[6] | (m[7] << 10) | (m[8] << 20) | ((((unsigned)E >> 4) & 3) << 30);
    unsigned w3 = m[9] | (m[10] << 10) | (m[11] << 20);

    u32x4 o = {w0, w1, w2, w3};
    patches[t] = o;
}

__global__ __launch_bounds__(256) void lp_se4(
    const float* __restrict__ xyz,
    const float* __restrict__ vdirs,
    const u32x4* __restrict__ patches,
    float* __restrict__ out,
    int N)
{
    __shared__ float sh[1536];

    int tid = threadIdx.x;
    int b0  = blockIdx.x * 256;
    int nPts = N - b0; nPts = nPts > 256 ? 256 : nPts;
    int nflt = nPts * 3;
    int base4 = (b0 * 3) >> 2;

    const vf4* x4 = (const vf4*)xyz;
    const vf4* d4 = (const vf4*)vdirs;
    if (tid * 4 < nflt) {
        vf4 vx = __builtin_nontemporal_load(&x4[base4 + tid]);
        ((vf4*)sh)[tid] = vx;
        vf4 vd = __builtin_nontemporal_load(&d4[base4 + tid]);
        ((vf4*)(sh + 768))[tid] = vd;
    }
    __syncthreads();

    float r = 0.0f, g = 0.0f, b = 0.0f;
    if (tid < nPts) {
        float x  = sh[3 * tid + 0];
        float y  = sh[3 * tid + 1];
        float z  = sh[3 * tid + 2];
        float dx = sh[768 + 3 * tid + 0];
        float dy = sh[768 + 3 * tid + 1];
        float dz = sh[768 + 3 * tid + 2];

        float ex0, ex1, ex2, ey0, ey1, ey2, ez0, ez1, ez2;
        int jx0, jx1, jx2, jy0, jy1, jy2, jz0, jz1, jz2;
        dimsort(x, ex0, ex1, ex2, jx0, jx1, jx2);
        dimsort(y, ey0, ey1, ey2, jy0, jy1, jy2);
        dimsort(z, ez0, ez1, ez2, jz0, jz1, jz2);

        int face, t00;
        float w00, w01, w10, w11;
        uv_setup(dx, dy, dz, face, t00, w00, w01, w10, w11);
        int cell = (face * 256 + t00) * 125;

        int X0 = jx0 * 25, X1 = jx1 * 25, X2 = jx2 * 25;
        int Y0 = jy0 * 5,  Y1 = jy1 * 5,  Y2 = jy2 * 5;
        int Z0 = jz0,      Z1 = jz1,      Z2 = jz2;

        // rank-0 is ALWAYS candidate 000; issue its (cached) gather before
        // the insert chain to overlap L2 latency with the selection VALU.
        int k0 = X0 + Y0 + Z0;
        u32x4 pw0 = patches[cell + k0];

        float exy00 = ex0 + ey0, exy10 = ex1 + ey0, exy01 = ex0 + ey1;
        float exy11 = ex1 + ey1, exy20 = ex2 + ey0, exy02 = ex0 + ey2;
        int   kxy10 = X1 + Y0,   kxy01 = X0 + Y1;
        int   kxy11 = X1 + Y1,   kxy20 = X2 + Y0,   kxy02 = X0 + Y2;
        int   kxy00 = X0 + Y0;

        float s0 = exy00 + ez0;
        float s1 = 1e30f, s2 = 1e30f, s3 = 1e30f;
        int   k1 = 0, k2 = 0, k3 = 0;

        { float d = exy10 + ez0; int L = kxy10 + Z0; INSERT3(d, L, s1, s2, s3, k1, k2, k3); }
        { float d = exy01 + ez0; int L = kxy01 + Z0; INSERT3(d, L, s1, s2, s3, k1, k2, k3); }
        { float d = exy00 + ez1; int L = kxy00 + Z1; INSERT3(d, L, s1, s2, s3, k1, k2, k3); }
        { float d = exy11 + ez0; int L = kxy11 + Z0; INSERT3(d, L, s1, s2, s3, k1, k2, k3); }
        { float d = exy10 + ez1; int L = kxy10 + Z1; INSERT3(d, L, s1, s2, s3, k1, k2, k3); }
        { float d = exy01 + ez1; int L = kxy01 + Z1; INSERT3(d, L, s1, s2, s3, k1, k2, k3); }
        { float d = exy20 + ez0; int L = kxy20 + Z0; INSERT3(d, L, s1, s2, s3, k1, k2, k3); }
        { float d = exy02 + ez0; int L = kxy02 + Z0; INSERT3(d, L, s1, s2, s3, k1, k2, k3); }
        { float d = exy00 + ez2; int L = kxy00 + Z2; INSERT3(d, L, s1, s2, s3, k1, k2, k3); }

        // remaining 3 gathers — plain cached loads (table stays L2-resident)
        u32x4 pw1 = patches[cell + k1];
        u32x4 pw2 = patches[cell + k2];
        u32x4 pw3 = patches[cell + k3];

        float w0 = fastrcp(fastsqrt(s0) + 1e-4f);
        float w1 = fastrcp(fastsqrt(s1) + 1e-4f);
        float w2 = fastrcp(fastsqrt(s2) + 1e-4f);
        float w3 = fastrcp(fastsqrt(s3) + 1e-4f);
        float wi = fastrcp(w0 + w1 + w2 + w3);
        w0 *= wi; w1 *= wi; w2 *= wi; w3 *= wi;

        decode_accum(pw0, w0, w00, w01, w10, w11, r, g, b);
        decode_accum(pw1, w1, w00, w01, w10, w11, r, g, b);
        decode_accum(pw2, w2, w00, w01, w10, w11, r, g, b);
        decode_accum(pw3, w3, w00, w01, w10, w11, r, g, b);
    }

    __syncthreads();
    if (tid < nPts) {
        sh[3 * tid + 0] = r;
        sh[3 * tid + 1] = g;
        sh[3 * tid + 2] = b;
    }
    __syncthreads();
    if (tid * 4 < nflt) {
        vf4* o4 = (vf4*)out;
        __builtin_nontemporal_store(((vf4*)sh)[tid], &o4[base4 + tid]);
    }
}

extern "C" void kernel_launch(void* const* d_in, const int* in_sizes, int n_in,
                              void* d_out, int out_size, void* d_ws, size_t ws_size,
                              hipStream_t stream) {
    const float* xyz  = (const float*)d_in[0];
    const float* vd   = (const float*)d_in[1];
    const float* cube = (const float*)d_in[2];
    float* outp = (float*)d_out;
    int N = in_sizes[0] / 3;
    int blocks = (N + 255) / 256;

    u32x4* patches = (u32x4*)d_ws;    // 3.07 MB
    hipLaunchKernelGGL(build_patches_se, dim3((NPATCH + 255) / 256), dim3(256), 0, stream,
                       cube, patches);
    hipLaunchKernelGGL(lp_se4, dim3(blocks), dim3(256), 0, stream,
                       xyz, vd, patches, outp, N);
}